// Round 11
// baseline (338.042 us; speedup 1.0000x reference)
//
#include <hip/hip_runtime.h>

typedef _Float16 f16;
typedef _Float16 f16x8 __attribute__((ext_vector_type(8)));
typedef float f32x4 __attribute__((ext_vector_type(4)));

#define MFMA16(a, b, c) __builtin_amdgcn_mfma_f32_16x16x32_f16((a), (b), (c), 0, 0, 0)

constexpr int SEQ   = 16;
constexpr int PLEN  = 15;
constexpr int BATCH = 32768;
constexpr int POSE  = 34;
constexpr int HD    = 64;
constexpr int GRPS  = 2;     // two independent 16-row chains per wave (R6-proven ILP)
constexpr int ROWS  = 16;    // rows per chain
constexpr int BROWS = GRPS * ROWS;  // 32 rows/block; grid 1024
constexpr int XROW  = 136;   // [h 0..63 | x 64..97 | 1.0 @98 | 0..127 | pad]

constexpr float LOG2E  = 1.4426950408889634f;
constexpr float LOG2E2 = 2.8853900817779268f;

__device__ __forceinline__ float rcpf(float x)   { return __builtin_amdgcn_rcpf(x); }
__device__ __forceinline__ float exp2f_(float x) { return __builtin_amdgcn_exp2f(x); }

// R9's body exactly. Launch bounds: (256) with NO min-waves arg — measured across
// R1..R10, the 2nd arg both caps residency (waves/EU == arg) and, at 4, forces the
// 64-VGPR tier (spill, FETCH 36->120MB). Natural alloc is ~112 VGPR <= 128 => the
// HW tier itself gives 4 waves/EU resident with no spill.
__global__ __launch_bounds__(256)
void lstm11(const float* __restrict__ obs,
            const float* __restrict__ Wih_e, const float* __restrict__ Whh_e,
            const float* __restrict__ b_e,
            const float* __restrict__ Wih_d, const float* __restrict__ Whh_d,
            const float* __restrict__ b_d,
            const float* __restrict__ fc_w, const float* __restrict__ fc_b,
            float* __restrict__ out)
{
    // [dbuf][chain][row][XROW] — 17408 B
    __shared__ f16 bfr[2 * GRPS * ROWS * XROW];

    const int tid  = threadIdx.x;
    const int lane = tid & 63;
    const int q    = tid >> 6;     // gate-column split
    const int l15  = lane & 15;
    const int l4   = lane >> 4;
    const int blkbase = blockIdx.x * BROWS;

    f16x8 Bw[4][4];   // [gate i/f/g/o][kf]
    float be[4];      // fused-decoder bias
    auto loadB = [&](const float* __restrict__ Wih, const float* __restrict__ Whh,
                     const float* __restrict__ b) {
        #pragma unroll
        for (int gg = 0; gg < 4; ++gg) {
            const int r = (gg * 4 + q) * 16 + l15;
            const float sc = (gg == 2) ? LOG2E2 : LOG2E;
            #pragma unroll
            for (int kf = 0; kf < 2; ++kf) {
                const float* src = Whh + r * HD + kf * 32 + l4 * 8;
                #pragma unroll
                for (int j = 0; j < 8; ++j) Bw[gg][kf][j] = (f16)(src[j] * sc);
            }
            {
                const float* src = Wih + r * POSE + l4 * 8;
                #pragma unroll
                for (int j = 0; j < 8; ++j) Bw[gg][2][j] = (f16)(src[j] * sc);
            }
            #pragma unroll
            for (int j = 0; j < 8; ++j) {
                const int k = 96 + l4 * 8 + j;
                float v = 0.f;
                if (k < 98)       v = Wih[r * POSE + (k - 64)];
                else if (k == 98) v = b[r];
                Bw[gg][3][j] = (f16)(v * sc);
            }
        }
    };

    // fused decoder: W_eff = Whh_d + Wih_d @ fc_w ; b_eff = b_d + Wih_d @ fc_b
    auto loadBeff = [&]() {
        #pragma unroll
        for (int gg = 0; gg < 4; ++gg) {
            const int r = (gg * 4 + q) * 16 + l15;
            const float sc = (gg == 2) ? LOG2E2 : LOG2E;
            #pragma unroll
            for (int kf = 0; kf < 2; ++kf) {
                float a8[8];
                const float* wh = Whh_d + r * HD + kf * 32 + l4 * 8;
                #pragma unroll
                for (int j = 0; j < 8; ++j) a8[j] = wh[j];
                for (int pp = 0; pp < POSE; ++pp) {
                    const float wp = Wih_d[r * POSE + pp];
                    const float* fw = fc_w + pp * HD + kf * 32 + l4 * 8;
                    #pragma unroll
                    for (int j = 0; j < 8; ++j) a8[j] += wp * fw[j];
                }
                #pragma unroll
                for (int j = 0; j < 8; ++j) Bw[gg][kf][j] = (f16)(a8[j] * sc);
            }
            float bb = b_d[r];
            for (int pp = 0; pp < POSE; ++pp) bb += Wih_d[r * POSE + pp] * fc_b[pp];
            be[gg] = bb * sc;
        }
    };

    auto stage_x = [&](int ts, int dstbuf) {
        const float* src = obs + ((size_t)ts * BATCH + blkbase) * POSE;  // 1088 contiguous f32
        #pragma unroll
        for (int it = 0; it < 5; ++it) {
            int i = it * 256 + tid;
            if (i < BROWS * POSE) {
                int row = i / POSE, col = i - row * POSE;
                bfr[((dstbuf * GRPS + (row >> 4)) * ROWS + (row & 15)) * XROW + HD + col] = (f16)src[i];
            }
        }
    };

    // fc weights / bias, register-resident
    const int  p    = q * 16 + l15;
    const bool fcok = (q < 3);
    f16x8 Bfc[2];
    #pragma unroll
    for (int kf = 0; kf < 2; ++kf)
        #pragma unroll
        for (int j = 0; j < 8; ++j)
            Bfc[kf][j] = (f16)((fcok && p < POSE) ? fc_w[p * HD + kf * 32 + l4 * 8 + j] : 0.f);
    const float fcb = (fcok && p < POSE) ? fc_b[p] : 0.f;

    loadB(Wih_e, Whh_e, b_e);

    // init: h0 = 0, bias col = 1.0 (both buffers)
    for (int i = tid; i < 2 * GRPS * ROWS * XROW; i += 256) {
        int c = i % XROW;
        bfr[i] = (c == 98) ? (f16)1.0f : (f16)0.0f;
    }
    __syncthreads();
    stage_x(0, 0);
    __syncthreads();

    f32x4 cst[GRPS];
    cst[0] = (f32x4)0.f;
    cst[1] = (f32x4)0.f;

    auto ldA4 = [&](int c, int sb, f16x8 (&a)[4]) {
        #pragma unroll
        for (int kf = 0; kf < 4; ++kf)
            a[kf] = *(const f16x8*)&bfr[((sb * GRPS + c) * ROWS + l15) * XROW + kf * 32 + l4 * 8];
    };
    auto ldA2 = [&](int c, int sb, f16x8 (&a)[2]) {
        #pragma unroll
        for (int kf = 0; kf < 2; ++kf)
            a[kf] = *(const f16x8*)&bfr[((sb * GRPS + c) * ROWS + l15) * XROW + kf * 32 + l4 * 8];
    };
    auto g128 = [&](const f16x8 (&a)[4], f32x4 (&acc)[4]) {
        #pragma unroll
        for (int gg = 0; gg < 4; ++gg) acc[gg] = (f32x4)0.f;
        #pragma unroll
        for (int kf = 0; kf < 4; ++kf)
            #pragma unroll
            for (int gg = 0; gg < 4; ++gg) acc[gg] = MFMA16(a[kf], Bw[gg][kf], acc[gg]);
    };
    auto g64 = [&](const f16x8 (&a)[2], f32x4 (&acc)[4]) {
        #pragma unroll
        for (int gg = 0; gg < 4; ++gg) acc[gg] = (f32x4){be[gg], be[gg], be[gg], be[gg]};
        #pragma unroll
        for (int kf = 0; kf < 2; ++kf)
            #pragma unroll
            for (int gg = 0; gg < 4; ++gg) acc[gg] = MFMA16(a[kf], Bw[gg][kf], acc[gg]);
    };
    auto nonlin = [&](int c, f32x4 (&acc)[4], int db) {
        #pragma unroll
        for (int r = 0; r < 4; ++r) {
            float si = rcpf(1.f + exp2f_(-acc[0][r]));
            float sf = rcpf(1.f + exp2f_(-acc[1][r]));
            float tg = 1.f - 2.f * rcpf(1.f + exp2f_(acc[2][r]));
            float so = rcpf(1.f + exp2f_(-acc[3][r]));
            float cc = sf * cst[c][r] + si * tg;
            float tc = 1.f - 2.f * rcpf(1.f + exp2f_(cc * LOG2E2));
            cst[c][r] = cc;
            bfr[((db * GRPS + c) * ROWS + l4 * 4 + r) * XROW + q * 16 + l15] = (f16)(so * tc);
        }
    };
    auto fcst = [&](int c, int sb, int t) {
        if (!fcok) return;
        f16x8 ah[2];
        #pragma unroll
        for (int kf = 0; kf < 2; ++kf)
            ah[kf] = *(const f16x8*)&bfr[((sb * GRPS + c) * ROWS + l15) * XROW + kf * 32 + l4 * 8];
        f32x4 o = {fcb, fcb, fcb, fcb};
        o = MFMA16(ah[0], Bfc[0], o);
        o = MFMA16(ah[1], Bfc[1], o);
        if (p < POSE) {
            float* ob = out + ((size_t)t * BATCH + blkbase + c * ROWS) * POSE;
            #pragma unroll
            for (int r = 0; r < 4; ++r) ob[(l4 * 4 + r) * POSE + p] = o[r];
        }
    };

    int cur = 0;

    // ======== encoder: 16 steps, R6-proven phase order, 1 barrier/step ========
    #pragma unroll 1
    for (int s = 0; s < SEQ; ++s) {
        const int nxt = cur ^ 1;
        f16x8 a0[4], a1[4];
        f32x4 acc0[4], acc1[4];
        ldA4(0, cur, a0); g128(a0, acc0);
        ldA4(1, cur, a1); g128(a1, acc1);
        { int ts = s + 1 < 15 ? s + 1 : 15; stage_x(ts, nxt); }
        nonlin(0, acc0, nxt);
        nonlin(1, acc1, nxt);
        __syncthreads();
        cur = nxt;
    }

    // ======== decoder step 0: original dec weights, K=128, x = obs[15] ========
    loadB(Wih_d, Whh_d, b_d);
    {
        const int nxt = cur ^ 1;
        f16x8 a0[4], a1[4];
        f32x4 acc0[4], acc1[4];
        ldA4(0, cur, a0); g128(a0, acc0);
        ldA4(1, cur, a1); g128(a1, acc1);
        nonlin(0, acc0, nxt);
        nonlin(1, acc1, nxt);
        __syncthreads();
        cur = nxt;
    }
    loadBeff();   // register-only switch to fused recurrence (K=64)

    // ======== decoder steps 1..14: K=64, fc(h_{t-1}) interleaved ========
    #pragma unroll 1
    for (int t = 1; t < PLEN; ++t) {
        const int nxt = cur ^ 1;
        f16x8 a0[2], a1[2];
        f32x4 acc0[4], acc1[4];
        ldA2(0, cur, a0); g64(a0, acc0);
        ldA2(1, cur, a1); g64(a1, acc1);
        fcst(0, cur, t - 1);          // out[t-1] = fc(h in buf[cur]); indep of nonlin
        fcst(1, cur, t - 1);
        nonlin(0, acc0, nxt);
        nonlin(1, acc1, nxt);
        __syncthreads();
        cur = nxt;
    }
    // final outputs: fc(h_14)
    fcst(0, cur, PLEN - 1);
    fcst(1, cur, PLEN - 1);
}

extern "C" void kernel_launch(void* const* d_in, const int* in_sizes, int n_in,
                              void* d_out, int out_size, void* d_ws, size_t ws_size,
                              hipStream_t stream) {
    const float* obs   = (const float*)d_in[0];
    const float* Wih_e = (const float*)d_in[1];
    const float* Whh_e = (const float*)d_in[2];
    const float* b_e   = (const float*)d_in[3];
    const float* Wih_d = (const float*)d_in[4];
    const float* Whh_d = (const float*)d_in[5];
    const float* b_d   = (const float*)d_in[6];
    const float* fc_w  = (const float*)d_in[7];
    const float* fc_b  = (const float*)d_in[8];
    float* out = (float*)d_out;

    lstm11<<<dim3(BATCH / BROWS), dim3(256), 0, stream>>>(
        obs, Wih_e, Whh_e, b_e, Wih_d, Whh_d, b_d, fc_w, fc_b, out);
}

// Round 12
// 160.344 us; speedup vs baseline: 2.1082x; 2.1082x over previous
//
#include <hip/hip_runtime.h>

typedef _Float16 f16;
typedef _Float16 f16x8 __attribute__((ext_vector_type(8)));
typedef float f32x4 __attribute__((ext_vector_type(4)));

#define MFMA16(a, b, c) __builtin_amdgcn_mfma_f32_16x16x32_f16((a), (b), (c), 0, 0, 0)

constexpr int SEQ   = 16;
constexpr int PLEN  = 15;
constexpr int BATCH = 32768;
constexpr int POSE  = 34;
constexpr int HD    = 64;
constexpr int GRPS  = 2;     // two independent 32-row chains per wave (R6-proven)
constexpr int ROWS  = 32;    // rows per chain (2 mf fragments)
constexpr int BROWS = GRPS * ROWS;  // 64 rows/block -> grid 512 -> one round at 2 blocks/CU
constexpr int XROW  = 136;   // [h 0..63 | x 64..97 | 1.0 @98 | 0..127 | pad]

constexpr float LOG2E  = 1.4426950408889634f;
constexpr float LOG2E2 = 2.8853900817779268f;

__device__ __forceinline__ float rcpf(float x)   { return __builtin_amdgcn_rcpf(x); }
__device__ __forceinline__ float exp2f_(float x) { return __builtin_amdgcn_exp2f(x); }

// R6 champion body + R9-validated fused decoder. (256,2): total per-wave regs
// (arch+acc) pack to <=256 -> 2 waves/EU, no spill (R1..R11 residency law).
__global__ __launch_bounds__(256, 2)
void lstm12(const float* __restrict__ obs,
            const float* __restrict__ Wih_e, const float* __restrict__ Whh_e,
            const float* __restrict__ b_e,
            const float* __restrict__ Wih_d, const float* __restrict__ Whh_d,
            const float* __restrict__ b_d,
            const float* __restrict__ fc_w, const float* __restrict__ fc_b,
            float* __restrict__ out)
{
    // [dbuf][chain][row][XROW] — 34816 B
    __shared__ f16 bfr[2 * GRPS * ROWS * XROW];

    const int tid  = threadIdx.x;
    const int lane = tid & 63;
    const int q    = tid >> 6;     // gate-column split: j = q*16 + l15
    const int l15  = lane & 15;
    const int l4   = lane >> 4;
    const int blkbase = blockIdx.x * BROWS;

    f16x8 Bw[4][4];   // [gate i/f/g/o][kf]
    float be[4];      // fused-decoder bias
    auto loadB = [&](const float* __restrict__ Wih, const float* __restrict__ Whh,
                     const float* __restrict__ b) {
        #pragma unroll
        for (int gg = 0; gg < 4; ++gg) {
            const int r = (gg * 4 + q) * 16 + l15;
            const float sc = (gg == 2) ? LOG2E2 : LOG2E;
            #pragma unroll
            for (int kf = 0; kf < 2; ++kf) {
                const float* src = Whh + r * HD + kf * 32 + l4 * 8;
                #pragma unroll
                for (int j = 0; j < 8; ++j) Bw[gg][kf][j] = (f16)(src[j] * sc);
            }
            {
                const float* src = Wih + r * POSE + l4 * 8;
                #pragma unroll
                for (int j = 0; j < 8; ++j) Bw[gg][2][j] = (f16)(src[j] * sc);
            }
            #pragma unroll
            for (int j = 0; j < 8; ++j) {
                const int k = 96 + l4 * 8 + j;
                float v = 0.f;
                if (k < 98)       v = Wih[r * POSE + (k - 64)];
                else if (k == 98) v = b[r];
                Bw[gg][3][j] = (f16)(v * sc);
            }
        }
    };

    // fused decoder: W_eff = Whh_d + Wih_d @ fc_w ; b_eff = b_d + Wih_d @ fc_b (R9-validated)
    auto loadBeff = [&]() {
        #pragma unroll
        for (int gg = 0; gg < 4; ++gg) {
            const int r = (gg * 4 + q) * 16 + l15;
            const float sc = (gg == 2) ? LOG2E2 : LOG2E;
            #pragma unroll
            for (int kf = 0; kf < 2; ++kf) {
                float a8[8];
                const float* wh = Whh_d + r * HD + kf * 32 + l4 * 8;
                #pragma unroll
                for (int j = 0; j < 8; ++j) a8[j] = wh[j];
                for (int pp = 0; pp < POSE; ++pp) {
                    const float wp = Wih_d[r * POSE + pp];
                    const float* fw = fc_w + pp * HD + kf * 32 + l4 * 8;
                    #pragma unroll
                    for (int j = 0; j < 8; ++j) a8[j] += wp * fw[j];
                }
                #pragma unroll
                for (int j = 0; j < 8; ++j) Bw[gg][kf][j] = (f16)(a8[j] * sc);
            }
            float bb = b_d[r];
            for (int pp = 0; pp < POSE; ++pp) bb += Wih_d[r * POSE + pp] * fc_b[pp];
            be[gg] = bb * sc;
        }
    };

    auto stage_x = [&](int ts, int dstbuf) {
        const float* src = obs + ((size_t)ts * BATCH + blkbase) * POSE;  // 2176 contiguous f32
        #pragma unroll
        for (int it = 0; it < 9; ++it) {
            int i = it * 256 + tid;
            if (i < BROWS * POSE) {
                int row = i / POSE, col = i - row * POSE;
                bfr[((dstbuf * GRPS + (row >> 5)) * ROWS + (row & 31)) * XROW + HD + col] = (f16)src[i];
            }
        }
    };

    // fc weights / bias, register-resident
    const int  p    = q * 16 + l15;
    const bool fcok = (q < 3);                 // WAVE-UNIFORM (R8's NaN = divergent MFMA guard)
    f16x8 Bfc[2];
    #pragma unroll
    for (int kf = 0; kf < 2; ++kf)
        #pragma unroll
        for (int j = 0; j < 8; ++j)
            Bfc[kf][j] = (f16)((fcok && p < POSE) ? fc_w[p * HD + kf * 32 + l4 * 8 + j] : 0.f);
    const float fcb = (fcok && p < POSE) ? fc_b[p] : 0.f;

    loadB(Wih_e, Whh_e, b_e);

    // init: h0 = 0, bias col = 1.0 (both buffers)
    for (int i = tid; i < 2 * GRPS * ROWS * XROW; i += 256) {
        int c = i % XROW;
        bfr[i] = (c == 98) ? (f16)1.0f : (f16)0.0f;
    }
    __syncthreads();
    stage_x(0, 0);
    __syncthreads();

    f32x4 cst[GRPS][2];   // per-chain, per-mf cell state
    #pragma unroll
    for (int g = 0; g < GRPS; ++g) { cst[g][0] = (f32x4)0.f; cst[g][1] = (f32x4)0.f; }

    auto ldA = [&](int c, int sb, f16x8 (&a)[2][4]) {
        #pragma unroll
        for (int mf = 0; mf < 2; ++mf)
            #pragma unroll
            for (int kf = 0; kf < 4; ++kf)
                a[mf][kf] = *(const f16x8*)&bfr[((sb * GRPS + c) * ROWS + mf * 16 + l15) * XROW + kf * 32 + l4 * 8];
    };
    auto ldA2 = [&](int c, int sb, f16x8 (&a)[2][2]) {
        #pragma unroll
        for (int mf = 0; mf < 2; ++mf)
            #pragma unroll
            for (int kf = 0; kf < 2; ++kf)
                a[mf][kf] = *(const f16x8*)&bfr[((sb * GRPS + c) * ROWS + mf * 16 + l15) * XROW + kf * 32 + l4 * 8];
    };
    auto g128 = [&](const f16x8 (&a)[2][4], f32x4 (&acc)[2][4]) {
        #pragma unroll
        for (int mf = 0; mf < 2; ++mf)
            #pragma unroll
            for (int gg = 0; gg < 4; ++gg) acc[mf][gg] = (f32x4)0.f;
        #pragma unroll
        for (int kf = 0; kf < 4; ++kf)
            #pragma unroll
            for (int gg = 0; gg < 4; ++gg) {
                acc[0][gg] = MFMA16(a[0][kf], Bw[gg][kf], acc[0][gg]);
                acc[1][gg] = MFMA16(a[1][kf], Bw[gg][kf], acc[1][gg]);
            }
    };
    auto g64 = [&](const f16x8 (&a)[2][2], f32x4 (&acc)[2][4]) {
        #pragma unroll
        for (int mf = 0; mf < 2; ++mf)
            #pragma unroll
            for (int gg = 0; gg < 4; ++gg) acc[mf][gg] = (f32x4){be[gg], be[gg], be[gg], be[gg]};
        #pragma unroll
        for (int kf = 0; kf < 2; ++kf)
            #pragma unroll
            for (int gg = 0; gg < 4; ++gg) {
                acc[0][gg] = MFMA16(a[0][kf], Bw[gg][kf], acc[0][gg]);
                acc[1][gg] = MFMA16(a[1][kf], Bw[gg][kf], acc[1][gg]);
            }
    };
    auto nonlin = [&](int c, f32x4 (&acc)[2][4], int db) {
        #pragma unroll
        for (int mf = 0; mf < 2; ++mf) {
            #pragma unroll
            for (int r = 0; r < 4; ++r) {
                float si = rcpf(1.f + exp2f_(-acc[mf][0][r]));
                float sf = rcpf(1.f + exp2f_(-acc[mf][1][r]));
                float tg = 1.f - 2.f * rcpf(1.f + exp2f_(acc[mf][2][r]));
                float so = rcpf(1.f + exp2f_(-acc[mf][3][r]));
                float cc = sf * cst[c][mf][r] + si * tg;
                float tc = 1.f - 2.f * rcpf(1.f + exp2f_(cc * LOG2E2));
                cst[c][mf][r] = cc;
                bfr[((db * GRPS + c) * ROWS + mf * 16 + l4 * 4 + r) * XROW + q * 16 + l15] = (f16)(so * tc);
            }
        }
    };
    // fc(h in buf[sb]) -> out[t]; fresh LDS reads (R9-validated form), wave-uniform guard
    auto fcst = [&](int c, int sb, int t) {
        if (!fcok) return;
        f16x8 ah[2][2];
        #pragma unroll
        for (int mf = 0; mf < 2; ++mf)
            #pragma unroll
            for (int kf = 0; kf < 2; ++kf)
                ah[mf][kf] = *(const f16x8*)&bfr[((sb * GRPS + c) * ROWS + mf * 16 + l15) * XROW + kf * 32 + l4 * 8];
        f32x4 o0 = {fcb, fcb, fcb, fcb}, o1 = {fcb, fcb, fcb, fcb};
        #pragma unroll
        for (int kf = 0; kf < 2; ++kf) {
            o0 = MFMA16(ah[0][kf], Bfc[kf], o0);
            o1 = MFMA16(ah[1][kf], Bfc[kf], o1);
        }
        if (p < POSE) {
            float* ob = out + ((size_t)t * BATCH + blkbase + c * ROWS) * POSE;
            #pragma unroll
            for (int r = 0; r < 4; ++r) {
                ob[(l4 * 4 + r) * POSE + p]      = o0[r];
                ob[(16 + l4 * 4 + r) * POSE + p] = o1[r];
            }
        }
    };

    int cur = 0;

    // ======== encoder: 16 steps, R6-proven phase order, 1 barrier/step ========
    #pragma unroll 1
    for (int s = 0; s < SEQ; ++s) {
        const int nxt = cur ^ 1;
        f16x8 a0[2][4], a1[2][4];
        f32x4 acc0[2][4], acc1[2][4];
        ldA(0, cur, a0); g128(a0, acc0);
        ldA(1, cur, a1); g128(a1, acc1);
        { int ts = s + 1 < 15 ? s + 1 : 15; stage_x(ts, nxt); }
        nonlin(0, acc0, nxt);
        nonlin(1, acc1, nxt);
        __syncthreads();
        cur = nxt;
    }

    // ======== decoder step 0: original dec weights, K=128, x = obs[15] ========
    loadB(Wih_d, Whh_d, b_d);
    {
        const int nxt = cur ^ 1;
        f16x8 a0[2][4], a1[2][4];
        f32x4 acc0[2][4], acc1[2][4];
        ldA(0, cur, a0); g128(a0, acc0);
        ldA(1, cur, a1); g128(a1, acc1);
        nonlin(0, acc0, nxt);
        nonlin(1, acc1, nxt);
        __syncthreads();
        cur = nxt;
    }
    loadBeff();   // register-only switch to fused recurrence (K=64)

    // ======== decoder steps 1..14: K=64, fc(h_{t-1}) fills the nonlin shadow ========
    #pragma unroll 1
    for (int t = 1; t < PLEN; ++t) {
        const int nxt = cur ^ 1;
        f16x8 a0[2][2], a1[2][2];
        f32x4 acc0[2][4], acc1[2][4];
        ldA2(0, cur, a0); g64(a0, acc0);
        ldA2(1, cur, a1); g64(a1, acc1);
        fcst(0, cur, t - 1);          // out[t-1] = fc(h in buf[cur]); indep of nonlin
        fcst(1, cur, t - 1);
        nonlin(0, acc0, nxt);
        nonlin(1, acc1, nxt);
        __syncthreads();
        cur = nxt;
    }
    // final outputs: fc(h_14)
    fcst(0, cur, PLEN - 1);
    fcst(1, cur, PLEN - 1);
}

extern "C" void kernel_launch(void* const* d_in, const int* in_sizes, int n_in,
                              void* d_out, int out_size, void* d_ws, size_t ws_size,
                              hipStream_t stream) {
    const float* obs   = (const float*)d_in[0];
    const float* Wih_e = (const float*)d_in[1];
    const float* Whh_e = (const float*)d_in[2];
    const float* b_e   = (const float*)d_in[3];
    const float* Wih_d = (const float*)d_in[4];
    const float* Whh_d = (const float*)d_in[5];
    const float* b_d   = (const float*)d_in[6];
    const float* fc_w  = (const float*)d_in[7];
    const float* fc_b  = (const float*)d_in[8];
    float* out = (float*)d_out;

    lstm12<<<dim3(BATCH / BROWS), dim3(256), 0, stream>>>(
        obs, Wih_e, Whh_e, b_e, Wih_d, Whh_d, b_d, fc_w, fc_b, out);
}

// Round 13
// 122.204 us; speedup vs baseline: 2.7662x; 1.3121x over previous
//
#include <hip/hip_runtime.h>

typedef _Float16 f16;
typedef _Float16 f16x8 __attribute__((ext_vector_type(8)));
typedef float f32x4 __attribute__((ext_vector_type(4)));

#define MFMA16(a, b, c) __builtin_amdgcn_mfma_f32_16x16x32_f16((a), (b), (c), 0, 0, 0)

constexpr int SEQ   = 16;
constexpr int PLEN  = 15;
constexpr int BATCH = 32768;
constexpr int POSE  = 34;
constexpr int HD    = 64;
constexpr int GRPS  = 2;     // two independent 32-row chains per wave (R6 champion)
constexpr int ROWS  = 32;    // rows per group
constexpr int BROWS = GRPS * ROWS;  // 64 rows per block
constexpr int XROW  = 136;   // [h 0..63 | x 64..97 | 1.0 @98 | 0..127 | pad]

constexpr float LOG2E   = 1.4426950408889634f;
constexpr float LOG2E2  = 2.8853900817779268f;
constexpr float NLOG2E2 = -2.8853900817779268f;

__device__ __forceinline__ float rcpf(float x)   { return __builtin_amdgcn_rcpf(x); }
__device__ __forceinline__ float exp2f_(float x) { return __builtin_amdgcn_exp2f(x); }

// R6 champion, verbatim, with ONE change: merged-rcp nonlinearity (7 trans/elem vs 10).
__global__ __launch_bounds__(256, 2)
void lstm13(const float* __restrict__ obs,
            const float* __restrict__ Wih_e, const float* __restrict__ Whh_e,
            const float* __restrict__ b_e,
            const float* __restrict__ Wih_d, const float* __restrict__ Whh_d,
            const float* __restrict__ b_d,
            const float* __restrict__ fc_w, const float* __restrict__ fc_b,
            float* __restrict__ out)
{
    // [dbuf][grp][row][XROW] activation rows — 34816 B
    __shared__ f16 bfr[2 * GRPS * ROWS * XROW];

    const int tid  = threadIdx.x;
    const int lane = tid & 63;
    const int q    = tid >> 6;     // gate-column split (j = q*16 + l15)
    const int l15  = lane & 15;
    const int l4   = lane >> 4;
    const int blkbase = blockIdx.x * BROWS;

    // ---- weight B-frags directly from global f32 ----
    f16x8 Bw[4][4];
    auto loadB = [&](const float* __restrict__ Wih, const float* __restrict__ Whh,
                     const float* __restrict__ b) {
        #pragma unroll
        for (int gg = 0; gg < 4; ++gg) {
            const int r = (gg * 4 + q) * 16 + l15;
            const float sc = (gg == 2) ? LOG2E2 : LOG2E;
            #pragma unroll
            for (int kf = 0; kf < 2; ++kf) {
                const float* src = Whh + r * HD + kf * 32 + l4 * 8;
                #pragma unroll
                for (int j = 0; j < 8; ++j) Bw[gg][kf][j] = (f16)(src[j] * sc);
            }
            {
                const float* src = Wih + r * POSE + l4 * 8;
                #pragma unroll
                for (int j = 0; j < 8; ++j) Bw[gg][2][j] = (f16)(src[j] * sc);
            }
            #pragma unroll
            for (int j = 0; j < 8; ++j) {
                const int k = 96 + l4 * 8 + j;
                float v = 0.f;
                if (k < 98)       v = Wih[r * POSE + (k - 64)];
                else if (k == 98) v = b[r];
                Bw[gg][3][j] = (f16)(v * sc);
            }
        }
    };
    loadB(Wih_e, Whh_e, b_e);

    auto stage_x = [&](int ts, int dstbuf) {
        const float* src = obs + ((size_t)ts * BATCH + blkbase) * POSE;  // 2176 contiguous f32
        #pragma unroll
        for (int it = 0; it < 9; ++it) {
            int i = it * 256 + tid;
            if (i < BROWS * POSE) {
                int row = i / POSE, col = i - row * POSE;
                bfr[((dstbuf * GRPS + (row >> 5)) * ROWS + (row & 31)) * XROW + HD + col] = (f16)src[i];
            }
        }
    };

    // fc weights / bias, register-resident
    const int  p    = q * 16 + l15;
    const bool fcok = (q < 3);
    f16x8 Bfc[2];
    #pragma unroll
    for (int kf = 0; kf < 2; ++kf)
        #pragma unroll
        for (int j = 0; j < 8; ++j)
            Bfc[kf][j] = (f16)((fcok && p < POSE) ? fc_w[p * HD + kf * 32 + l4 * 8 + j] : 0.f);
    const float fcb = (fcok && p < POSE) ? fc_b[p] : 0.f;

    // init: h0 = 0, bias col = 1.0
    for (int i = tid; i < 2 * GRPS * ROWS * XROW; i += 256) {
        int c = i % XROW;
        bfr[i] = (c == 98) ? (f16)1.0f : (f16)0.0f;
    }
    __syncthreads();
    stage_x(0, 0);
    __syncthreads();

    f32x4 cst[GRPS][2];   // per-group cell state
    #pragma unroll
    for (int g = 0; g < GRPS; ++g) { cst[g][0] = (f32x4)0.f; cst[g][1] = (f32x4)0.f; }

    auto ldA = [&](int grp, int srcbuf, f16x8 (&a)[2][4]) {
        #pragma unroll
        for (int mf = 0; mf < 2; ++mf)
            #pragma unroll
            for (int kf = 0; kf < 4; ++kf)
                a[mf][kf] = *(const f16x8*)&bfr[((srcbuf * GRPS + grp) * ROWS + mf * 16 + l15) * XROW + kf * 32 + l4 * 8];
    };
    auto gates = [&](const f16x8 (&a)[2][4], f32x4 (&acc)[2][4]) {
        #pragma unroll
        for (int mf = 0; mf < 2; ++mf)
            #pragma unroll
            for (int gg = 0; gg < 4; ++gg) acc[mf][gg] = (f32x4)0.f;
        #pragma unroll
        for (int kf = 0; kf < 4; ++kf)
            #pragma unroll
            for (int gg = 0; gg < 4; ++gg) {
                acc[0][gg] = MFMA16(a[0][kf], Bw[gg][kf], acc[0][gg]);
                acc[1][gg] = MFMA16(a[1][kf], Bw[gg][kf], acc[1][gg]);
            }
    };
    // merged-rcp nonlin: 5 exp2 + 2 rcp per element.
    //   c' = [c*(1+Ei)(1+Eg) + (1-Eg)(1+Ef)] / [(1+Ef)(1+Ei)(1+Eg)]
    //   h  = (1-Ec) / [(1+Eo)(1+Ec)],  Ec = e^{-2c'}
    // (identical math to sigmoid/tanh form; inf-inf hazard needs |gate|>~44,
    //  weights bounded +-0.125 => |gate| <~ 15. f32 intermediates.)
    auto nonlin = [&](int grp, f32x4 (&acc)[2][4], int dstbuf) {
        #pragma unroll
        for (int mf = 0; mf < 2; ++mf) {
            #pragma unroll
            for (int r = 0; r < 4; ++r) {
                float Ei = exp2f_(-acc[mf][0][r]);   // e^{-i}
                float Ef = exp2f_(-acc[mf][1][r]);   // e^{-f}
                float Eg = exp2f_(-acc[mf][2][r]);   // e^{-2g} (g pre-scaled by 2log2e)
                float Eo = exp2f_(-acc[mf][3][r]);   // e^{-o}
                float pf = 1.f + Ef;
                float P  = (1.f + Ei) * (1.f + Eg);
                float cc = (cst[grp][mf][r] * P + (1.f - Eg) * pf) * rcpf(pf * P);
                float Ec = exp2f_(cc * NLOG2E2);     // e^{-2c'}
                float h  = (1.f - Ec) * rcpf((1.f + Eo) * (1.f + Ec));
                cst[grp][mf][r] = cc;
                bfr[((dstbuf * GRPS + grp) * ROWS + mf * 16 + l4 * 4 + r) * XROW + q * 16 + l15] = (f16)h;
            }
        }
    };
    auto fc_step = [&](int grp, int srcbuf, int t) {
        if (!fcok) return;
        f16x8 ah[2][2];
        #pragma unroll
        for (int mf = 0; mf < 2; ++mf)
            #pragma unroll
            for (int kf = 0; kf < 2; ++kf)
                ah[mf][kf] = *(const f16x8*)&bfr[((srcbuf * GRPS + grp) * ROWS + mf * 16 + l15) * XROW + kf * 32 + l4 * 8];
        f32x4 o0 = {fcb, fcb, fcb, fcb}, o1 = {fcb, fcb, fcb, fcb};
        #pragma unroll
        for (int kf = 0; kf < 2; ++kf) {
            o0 = MFMA16(ah[0][kf], Bfc[kf], o0);
            o1 = MFMA16(ah[1][kf], Bfc[kf], o1);
        }
        if (p < POSE) {
            float* ob = out + ((size_t)t * BATCH + blkbase + grp * ROWS) * POSE;
            #pragma unroll
            for (int r = 0; r < 4; ++r) {
                int r0 = l4 * 4 + r, r1 = 16 + l4 * 4 + r;
                ob[r0 * POSE + p] = o0[r];
                ob[r1 * POSE + p] = o1[r];
                bfr[((srcbuf * GRPS + grp) * ROWS + r0) * XROW + HD + p] = (f16)o0[r];  // feedback
                bfr[((srcbuf * GRPS + grp) * ROWS + r1) * XROW + HD + p] = (f16)o1[r];
            }
        }
    };

    int cur = 0;

    // ======== encoder: 16 steps, 1 barrier each, 2 chains interleaved ========
    #pragma unroll 1
    for (int s = 0; s < SEQ; ++s) {
        const int nxt = cur ^ 1;
        f16x8 aA[2][4], aB[2][4];
        f32x4 accA[2][4], accB[2][4];
        ldA(0, cur, aA);
        gates(aA, accA);
        ldA(1, cur, aB);
        gates(aB, accB);              // independent of nonlin(0) — overlaps its trans chain
        { int ts = s + 1 < 15 ? s + 1 : 15; stage_x(ts, nxt); }
        nonlin(0, accA, nxt);
        nonlin(1, accB, nxt);
        __syncthreads();
        cur = nxt;
    }

    // ======== decoder: 15 steps (R6 structure, per group) ========
    loadB(Wih_d, Whh_d, b_d);
    #pragma unroll 1
    for (int t = 0; t < PLEN; ++t) {
        const int nxt = cur ^ 1;
        f16x8 aA[2][4], aB[2][4];
        f32x4 accA[2][4], accB[2][4];
        ldA(0, cur, aA);
        gates(aA, accA);
        ldA(1, cur, aB);
        gates(aB, accB);
        nonlin(0, accA, nxt);
        nonlin(1, accB, nxt);
        __syncthreads();              // h complete -> fc reads full 64-wide h
        fc_step(0, nxt, t);           // writes out + x-feedback into buf[nxt]
        fc_step(1, nxt, t);
        __syncthreads();              // feedback visible before next step's A-reads
        cur = nxt;
    }
}

extern "C" void kernel_launch(void* const* d_in, const int* in_sizes, int n_in,
                              void* d_out, int out_size, void* d_ws, size_t ws_size,
                              hipStream_t stream) {
    const float* obs   = (const float*)d_in[0];
    const float* Wih_e = (const float*)d_in[1];
    const float* Whh_e = (const float*)d_in[2];
    const float* b_e   = (const float*)d_in[3];
    const float* Wih_d = (const float*)d_in[4];
    const float* Whh_d = (const float*)d_in[5];
    const float* b_d   = (const float*)d_in[6];
    const float* fc_w  = (const float*)d_in[7];
    const float* fc_b  = (const float*)d_in[8];
    float* out = (float*)d_out;

    lstm13<<<dim3(BATCH / BROWS), dim3(256), 0, stream>>>(
        obs, Wih_e, Whh_e, b_e, Wih_d, Whh_d, b_d, fc_w, fc_b, out);
}